// Round 2
// baseline (281.179 us; speedup 1.0000x reference)
//
#include <hip/hip_runtime.h>

// Problem constants (fp32 throughout):
//   y:          (4, 64, 8, 16)            = 32768
//   pairwise_g: (4, 64, 64, 8, 8, 48)     = 50331648  (201.3 MB -> HBM-bound)
//   Wy: (32,1)  by: (1,)  Wg: (48,1)  bg: (1,)
//   out k: (4, 64, 64, 8, 8, 1)           = 1048576
//
// k[b,p1,p2,s1,s2] = dot(g[b,p1,p2,s1,s2,:], Wg) + bg + by
//                    + dot(y[b,p2,s2,:], Wy[:16])     (a-term, indexed p2,s2)
//                    + dot(y[b,p1,s1,:], Wy[16:])     (c-term, indexed p1,s1)
//
// Roofline: 201 MB read + 4 MB write ≈ 33 us at 6.3 TB/s. Memory-bound.

#define NBPS 2048            // B*P*S = 4*64*8
#define NOUT 1048576         // B*P*P*S*S

// Pre-pass: a[i] = y[i]·Wy[:16] + by + bg ; c[i] = y[i]·Wy[16:]
// ws is re-poisoned 0xAA before every timed launch -> must recompute each call.
__global__ __launch_bounds__(256) void precompute_kernel(
    const float* __restrict__ y,
    const float* __restrict__ Wy,
    const float* __restrict__ by,
    const float* __restrict__ bg,
    float* __restrict__ a,
    float* __restrict__ c) {
    int i = blockIdx.x * 256 + threadIdx.x;
    if (i >= NBPS) return;
    const float4* yv = reinterpret_cast<const float4*>(y + i * 16);
    const float4* w1 = reinterpret_cast<const float4*>(Wy);        // Wy[0:16]
    const float4* w2 = reinterpret_cast<const float4*>(Wy + 16);   // Wy[16:32]
    float sa = 0.f, sc = 0.f;
#pragma unroll
    for (int j = 0; j < 4; ++j) {
        float4 v = yv[j];
        float4 u1 = w1[j];
        float4 u2 = w2[j];
        sa += v.x * u1.x + v.y * u1.y + v.z * u1.z + v.w * u1.w;
        sc += v.x * u2.x + v.y * u2.y + v.z * u2.z + v.w * u2.w;
    }
    a[i] = sa + by[0] + bg[0];   // fold both biases into the a-term
    c[i] = sc;
}

// Main: 1 thread = 1 output. 12 float4 loads issued back-to-back (48 VGPRs
// of in-flight data -> deep memory pipeline), then a 48-wide FMA dot with
// Wg (wave-uniform, cache-resident), epilogue adds the precomputed a/c
// terms, store is 1 dword/lane fully coalesced. Per-lane g range is 192 B
// contiguous; across the 12 consecutive load instructions every HBM sector
// of the wave's 12 KB window is requested exactly once.
__global__ __launch_bounds__(256) void main_kernel(
    const float* __restrict__ g,
    const float* __restrict__ Wg,
    const float* __restrict__ a,
    const float* __restrict__ c,
    float* __restrict__ out) {
    int o = blockIdx.x * 256 + threadIdx.x;   // grid exactly covers NOUT

    const float4* gv = reinterpret_cast<const float4*>(g + (size_t)o * 48);
    const float4* wv = reinterpret_cast<const float4*>(Wg);

    float4 v[12];
#pragma unroll
    for (int j = 0; j < 12; ++j) v[j] = gv[j];   // all loads in flight first

    float s0 = 0.f, s1 = 0.f, s2 = 0.f, s3 = 0.f;
#pragma unroll
    for (int j = 0; j < 12; j += 4) {
        float4 w0 = wv[j], w1 = wv[j + 1], w2 = wv[j + 2], w3 = wv[j + 3];
        s0 += v[j].x * w0.x + v[j].y * w0.y + v[j].z * w0.z + v[j].w * w0.w;
        s1 += v[j+1].x * w1.x + v[j+1].y * w1.y + v[j+1].z * w1.z + v[j+1].w * w1.w;
        s2 += v[j+2].x * w2.x + v[j+2].y * w2.y + v[j+2].z * w2.z + v[j+2].w * w2.w;
        s3 += v[j+3].x * w3.x + v[j+3].y * w3.y + v[j+3].z * w3.z + v[j+3].w * w3.w;
    }
    float s = (s0 + s1) + (s2 + s3);

    // o = ((((b*64 + p1)*64 + p2)*8 + s1)*8 + s2)
    int is2 = o & 7;
    int is1 = (o >> 3) & 7;
    int p2  = (o >> 6) & 63;
    int p1  = (o >> 12) & 63;
    int b   = o >> 18;
    float av = a[((b << 6) + p2) * 8 + is2];
    float cv = c[((b << 6) + p1) * 8 + is1];
    out[o] = s + av + cv;
}

extern "C" void kernel_launch(void* const* d_in, const int* in_sizes, int n_in,
                              void* d_out, int out_size, void* d_ws, size_t ws_size,
                              hipStream_t stream) {
    const float* y  = (const float*)d_in[0];
    const float* g  = (const float*)d_in[1];
    const float* Wy = (const float*)d_in[2];
    const float* by = (const float*)d_in[3];
    const float* Wg = (const float*)d_in[4];
    const float* bg = (const float*)d_in[5];
    float* out = (float*)d_out;

    float* a = (float*)d_ws;          // NBPS floats
    float* c = a + NBPS;              // NBPS floats (16 KB total in ws)

    precompute_kernel<<<(NBPS + 255) / 256, 256, 0, stream>>>(y, Wy, by, bg, a, c);

    main_kernel<<<NOUT / 256, 256, 0, stream>>>(g, Wg, a, c, out);
}